// Round 7
// baseline (162.363 us; speedup 1.0000x reference)
//
#include <hip/hip_runtime.h>

#define N_NODES 50000
#define N_EDGES 800000
#define D_FEAT  64
#define BATCH   2

#define SCAN_BLK 1024
#define N_SBLK   ((N_NODES + SCAN_BLK - 1) / SCAN_BLK)   // 49

typedef float nfloat2 __attribute__((ext_vector_type(2)));
typedef float nfloat4 __attribute__((ext_vector_type(4)));

// ---------------- workspace layout (bytes, stride-dependent) ----------------
// cursor : N*cs ints   @ 0     (cs=16 -> one cursor per 64B line, kills atomic
//                               line contention; cs=1 compact fallback)
// bsum   : 49 ints     @ cur_bytes
// boff   : 49 ints     @ cur_bytes + 256
// recs   : E nfloat4   @ cur_bytes + 512   {src_as_float, w0, w1, unused}

__global__ __launch_bounds__(256) void hist_kernel(const int* __restrict__ ei,
                                                   int* __restrict__ cnt,
                                                   const int cs) {
    const int e0 = blockIdx.x * 512 + threadIdx.x;
    #pragma unroll
    for (int k = 0; k < 2; ++k) {
        const int e = e0 + k * 256;
        if (e < N_EDGES)
            atomicAdd(&cnt[__builtin_nontemporal_load(ei + N_EDGES + e) * cs], 1);
    }
}

// In-place per-block exclusive scan of counts; block totals -> bsum.
__global__ __launch_bounds__(SCAN_BLK) void scan_blocks(int* __restrict__ cnt,
                                                        int* __restrict__ bsum,
                                                        const int cs) {
    const int gid  = blockIdx.x * SCAN_BLK + threadIdx.x;
    const int wid  = threadIdx.x >> 6;
    const int lane = threadIdx.x & 63;
    int v = (gid < N_NODES) ? cnt[gid * cs] : 0;

    int x = v;
    #pragma unroll
    for (int s = 1; s < 64; s <<= 1) {
        int t = __shfl_up(x, s, 64);
        if (lane >= s) x += t;
    }
    __shared__ int wsum[16];
    if (lane == 63) wsum[wid] = x;
    __syncthreads();
    if (wid == 0) {
        int y = (lane < 16) ? wsum[lane] : 0;
        #pragma unroll
        for (int s = 1; s < 16; s <<= 1) {
            int t = __shfl_up(y, s, 64);
            if (lane >= s) y += t;
        }
        if (lane < 16) wsum[lane] = y;
    }
    __syncthreads();
    const int woff = (wid > 0) ? wsum[wid - 1] : 0;
    const int incl = x + woff;
    if (gid < N_NODES) cnt[gid * cs] = incl - v;                 // block-local exclusive
    if (threadIdx.x == SCAN_BLK - 1) bsum[blockIdx.x] = incl;    // block total
}

// Exclusive scan of 49 block totals (one wave).
__global__ __launch_bounds__(64) void scan_tops(const int* __restrict__ bsum,
                                                int* __restrict__ boff) {
    const int lane = threadIdx.x;
    int v = (lane < N_SBLK) ? bsum[lane] : 0;
    int x = v;
    #pragma unroll
    for (int s = 1; s < 64; s <<= 1) {
        int t = __shfl_up(x, s, 64);
        if (lane >= s) x += t;
    }
    if (lane < N_SBLK) boff[lane] = x - v;
}

// Counting-sort scatter: one packed 16-B record per edge; 2 edges/thread MLP.
__global__ __launch_bounds__(256) void scatter_pack(const int* __restrict__ ei,
                                                    const float* __restrict__ w,
                                                    int* __restrict__ cursor,
                                                    const int* __restrict__ boff,
                                                    nfloat4* __restrict__ recs,
                                                    const int cs) {
    const int e0 = blockIdx.x * 512 + threadIdx.x;
    #pragma unroll
    for (int k = 0; k < 2; ++k) {
        const int e = e0 + k * 256;
        if (e >= N_EDGES) continue;
        const int src = __builtin_nontemporal_load(ei + e);
        const int dst = __builtin_nontemporal_load(ei + N_EDGES + e);
        const nfloat2 wv = __builtin_nontemporal_load((const nfloat2*)(w + 2 * e));
        const int pos = atomicAdd(&cursor[dst * cs], 1) + boff[dst >> 10];
        nfloat4 rec;
        rec.x = __int_as_float(src);
        rec.y = wv.x;
        rec.z = wv.y;
        rec.w = 0.f;
        recs[pos] = rec;
    }
}

// One wave per node; lanes cooperatively load 64 packed records, broadcast
// via shfl; edge loop hand-unrolled x8 -> 16 state loads in flight.
__global__ __launch_bounds__(256) void gather_kernel(const float* __restrict__ state,
                                                     const int* __restrict__ cursor,
                                                     const int* __restrict__ boff,
                                                     const nfloat4* __restrict__ recs,
                                                     float* __restrict__ out,
                                                     const int cs) {
    const int n = blockIdx.x * 4 + (threadIdx.x >> 6);
    const int d = threadIdx.x & 63;
    if (n >= N_NODES) return;
    const size_t plane = (size_t)N_NODES * D_FEAT;

    // cursor[m*cs] (post-scatter) = local_start[m]+count[m]; +boff = global end[m]
    const int j0 = (n > 0) ? (cursor[(n - 1) * cs] + boff[(n - 1) >> 10]) : 0;
    const int j1 = cursor[n * cs] + boff[n >> 10];

    float a0 = 0.f, a1 = 0.f;
    for (int base = j0; base < j1; base += 64) {
        const int cnt = min(64, j1 - base);
        nfloat4 r = (nfloat4)(0.f);
        if (d < cnt) r = __builtin_nontemporal_load(recs + base + d);

        int j = 0;
        for (; j + 8 <= cnt; j += 8) {
            int   s[8]; float wx[8], wy[8], v0[8], v1[8];
            #pragma unroll
            for (int u = 0; u < 8; ++u) {
                s[u]  = __shfl(__float_as_int(r.x), j + u, 64);
                wx[u] = __shfl(r.y, j + u, 64);
                wy[u] = __shfl(r.z, j + u, 64);
            }
            #pragma unroll
            for (int u = 0; u < 8; ++u) {
                v0[u] = state[(size_t)s[u] * D_FEAT + d];
                v1[u] = state[plane + (size_t)s[u] * D_FEAT + d];
            }
            #pragma unroll
            for (int u = 0; u < 8; ++u) {
                a0 += v0[u] * wx[u];
                a1 += v1[u] * wy[u];
            }
        }
        for (; j < cnt; ++j) {
            const int   s  = __shfl(__float_as_int(r.x), j, 64);
            const float wx = __shfl(r.y, j, 64);
            const float wy = __shfl(r.z, j, 64);
            a0 += state[(size_t)s * D_FEAT + d]         * wx;
            a1 += state[plane + (size_t)s * D_FEAT + d] * wy;
        }
    }
    __builtin_nontemporal_store(a0, out + (size_t)n * D_FEAT + d);
    __builtin_nontemporal_store(a1, out + plane + (size_t)n * D_FEAT + d);
}

// ---------------- fallback (ws too small): round-1 atomic kernel ----------------
__global__ __launch_bounds__(256) void scatter_add_kernel(
    const float* __restrict__ state, const int* __restrict__ edge_index,
    const float* __restrict__ weight, float* __restrict__ out) {
    const int e = blockIdx.x * 4 + (threadIdx.x >> 6);
    const int d = threadIdx.x & 63;
    if (e >= N_EDGES) return;
    const int src = edge_index[e];
    const int dst = edge_index[N_EDGES + e];
    const float w0 = weight[e * BATCH + 0];
    const float w1 = weight[e * BATCH + 1];
    const size_t plane = (size_t)N_NODES * D_FEAT;
    const float s0 = state[(size_t)src * D_FEAT + d];
    const float s1 = state[plane + (size_t)src * D_FEAT + d];
    atomicAdd(out + (size_t)dst * D_FEAT + d,         s0 * w0);
    atomicAdd(out + plane + (size_t)dst * D_FEAT + d, s1 * w1);
}

extern "C" void kernel_launch(void* const* d_in, const int* in_sizes, int n_in,
                              void* d_out, int out_size, void* d_ws, size_t ws_size,
                              hipStream_t stream) {
    const float* state      = (const float*)d_in[0];
    const int*   edge_index = (const int*)d_in[1];
    const float* weight     = (const float*)d_in[2];
    float*       out        = (float*)d_out;

    // Pick cursor stride: 16 (one per 64B line, no atomic line contention)
    // if workspace allows, else 1 (compact), else atomic fallback.
    int cs = 0;
    for (int try_cs = 16; try_cs >= 1; try_cs >>= 4) {
        size_t cur_bytes = (size_t)N_NODES * try_cs * sizeof(int);
        size_t need = cur_bytes + 512 + (size_t)N_EDGES * 16;
        if (ws_size >= need) { cs = try_cs; break; }
    }

    if (cs > 0) {
        char* ws = (char*)d_ws;
        const size_t cur_bytes = (size_t)N_NODES * cs * sizeof(int);
        int*     cursor = (int*)ws;
        int*     bsum   = (int*)(ws + cur_bytes);
        int*     boff   = (int*)(ws + cur_bytes + 256);
        nfloat4* recs   = (nfloat4*)(ws + cur_bytes + 512);

        (void)hipMemsetAsync(cursor, 0, cur_bytes, stream);

        dim3 eblk(256), egrd2((N_EDGES + 511) / 512);
        hipLaunchKernelGGL(hist_kernel, egrd2, eblk, 0, stream, edge_index, cursor, cs);
        hipLaunchKernelGGL(scan_blocks, dim3(N_SBLK), dim3(SCAN_BLK), 0, stream,
                           cursor, bsum, cs);
        hipLaunchKernelGGL(scan_tops, dim3(1), dim3(64), 0, stream, bsum, boff);
        hipLaunchKernelGGL(scatter_pack, egrd2, eblk, 0, stream,
                           edge_index, weight, cursor, boff, recs, cs);
        hipLaunchKernelGGL(gather_kernel, dim3((N_NODES + 3) / 4), dim3(256), 0, stream,
                           state, cursor, boff, recs, out, cs);
    } else {
        (void)hipMemsetAsync(out, 0, (size_t)out_size * sizeof(float), stream);
        hipLaunchKernelGGL(scatter_add_kernel, dim3((N_EDGES + 3) / 4), dim3(256), 0, stream,
                           state, edge_index, weight, out);
    }
}